// Round 1
// baseline (191.945 us; speedup 1.0000x reference)
//
#include <hip/hip_runtime.h>

// CenterLoss: loss = (1/B) * sum_j [ sum_{i: l_i=j} ||f_i - c_j||^2 / (n_j * D) ]
// B=65536, D=512, C=1000, fp32 in / fp32 scalar out. Memory-bound (128 MiB read).

#define WAVE 64

// One wave per sample. Lanes cooperatively load the sample row + its center row
// as float4 (coalesced, 16B/lane), reduce squared distance across the wave,
// lane 0 atomically accumulates into per-class sum/count.
__global__ __launch_bounds__(256) void center_dist_kernel(
    const float* __restrict__ features,   // [batch, feat]
    const float* __restrict__ centers,    // [nclass, feat]
    const int*   __restrict__ labels,     // [batch]
    float* __restrict__ sums,             // [nclass]
    float* __restrict__ counts,           // [nclass]
    int batch, int feat)
{
    const int wave_in_block = threadIdx.x >> 6;          // 0..3
    const int lane          = threadIdx.x & 63;
    const int sample        = blockIdx.x * 4 + wave_in_block;
    if (sample >= batch) return;

    const int label = labels[sample];

    const float4* __restrict__ f4 =
        (const float4*)(features + (size_t)sample * feat);
    const float4* __restrict__ c4 =
        (const float4*)(centers + (size_t)label * feat);

    // feat=512 -> 128 float4 per row -> 2 per lane
    float acc = 0.0f;
    const int n4 = feat >> 2;                            // 128
#pragma unroll 2
    for (int idx = lane; idx < n4; idx += WAVE) {
        float4 fv = f4[idx];
        float4 cv = c4[idx];
        float dx = fv.x - cv.x;
        float dy = fv.y - cv.y;
        float dz = fv.z - cv.z;
        float dw = fv.w - cv.w;
        acc += dx * dx + dy * dy;
        acc += dz * dz + dw * dw;
    }

    // wave-64 butterfly reduce
#pragma unroll
    for (int off = 32; off > 0; off >>= 1)
        acc += __shfl_down(acc, off, WAVE);

    if (lane == 0) {
        atomicAdd(&sums[label], acc);
        atomicAdd(&counts[label], 1.0f);
    }
}

// Single-block reduction over classes.
__global__ __launch_bounds__(256) void center_finalize_kernel(
    const float* __restrict__ sums,
    const float* __restrict__ counts,
    float* __restrict__ out,
    int nclass, int feat, int batch)
{
    float acc = 0.0f;
    for (int j = threadIdx.x; j < nclass; j += blockDim.x) {
        float n = counts[j];
        if (n > 0.0f) acc += sums[j] / (n * (float)feat);
    }
    // wave reduce
#pragma unroll
    for (int off = 32; off > 0; off >>= 1)
        acc += __shfl_down(acc, off, WAVE);

    __shared__ float warp_part[4];
    const int lane = threadIdx.x & 63;
    const int wid  = threadIdx.x >> 6;
    if (lane == 0) warp_part[wid] = acc;
    __syncthreads();

    if (threadIdx.x == 0) {
        float total = warp_part[0] + warp_part[1] + warp_part[2] + warp_part[3];
        out[0] = total / (float)batch;
    }
}

extern "C" void kernel_launch(void* const* d_in, const int* in_sizes, int n_in,
                              void* d_out, int out_size, void* d_ws, size_t ws_size,
                              hipStream_t stream) {
    const float* features = (const float*)d_in[0];
    const float* centers  = (const float*)d_in[1];
    const int*   labels   = (const int*)d_in[2];

    const int batch  = in_sizes[2];                 // 65536
    const int feat   = in_sizes[0] / batch;         // 512
    const int nclass = in_sizes[1] / feat;          // 1000

    float* sums   = (float*)d_ws;
    float* counts = sums + nclass;

    // zero the accumulators (ws is poisoned to 0xAA before every call)
    hipMemsetAsync(d_ws, 0, (size_t)2 * nclass * sizeof(float), stream);

    const int blocks = (batch + 3) / 4;             // 4 waves (samples) per block
    center_dist_kernel<<<blocks, 256, 0, stream>>>(
        features, centers, labels, sums, counts, batch, feat);

    center_finalize_kernel<<<1, 256, 0, stream>>>(
        sums, counts, (float*)d_out, nclass, feat, batch);
}